// Round 4
// baseline (346.935 us; speedup 1.0000x reference)
//
#include <hip/hip_runtime.h>

namespace {

typedef _Float16 half_t;
typedef _Float16 half2_t __attribute__((ext_vector_type(2)));
typedef _Float16 half4_t __attribute__((ext_vector_type(4)));

constexpr int Wd = 160, Hd = 192, Dd = 160;
constexpr int TX = 16, TY = 16, CZ = 20;
constexpr int HW = Hd * Wd;
constexpr int LIVE = CZ + 8;               // 28 slices per block
constexpr float INV_K = 1.0f / 729.0f;
constexpr float INV_TOT = 1.0f / 9830400.0f;   // 2*160*192*160
constexpr int R4 = 17;     // xs4h row stride in half4 units (16 cols + 1 pad)
constexpr int RTH = 68;    // xsTh row stride in half units (x at 4*x, stride-4 like xs4h)
constexpr int ROWS = 26;   // 24 halo rows + 2 pad rows absorbing lanes 240..255

// Fields f: 0=II 1=IT 2=TT 3=I (xs4h half4) 4=T (xsTh). T scaled (t+1)*0.5;
// zero padding applied AFTER scaling (OOB masks folded into fma coefficients).
// Planes stored fp16 (RNE): NCC is scale-invariant, quantization bias cancels;
// worst-case ~2e-4 rel on cc -> ~3e-7 abs on output vs 2.8e-5 threshold.

__global__ __launch_bounds__(256, 5)
void ncc_main(const float* __restrict__ inp, const float* __restrict__ tgt,
              float* __restrict__ out)
{
    __shared__ half4_t xs4h[2][ROWS * R4];   // 2 x 3536 B
    __shared__ half_t  xsTh[2][ROWS * RTH];  // 2 x 3536 B
    __shared__ float   red[4];

    const int tid = threadIdx.x;
    const int n  = (int)blockIdx.z >> 3;
    const int zc = (int)blockIdx.z & 7;
    const int x0 = blockIdx.x * TX, y0 = blockIdx.y * TY, z0 = zc * CZ;

    // ---- phase-1 decode: (row r 0..25) x (half h) x (field f)
    const int f = tid % 5;
    const int j = tid / 5;
    const int r = j >> 1, h = j & 1;
    const int gy = y0 - 4 + r;
    const bool yok = (tid < 240) && (gy >= 0) && (gy < Hd);
    const int gyc = min(max(gy, 0), Hd - 1);
    const int gxb = x0 - 4 + 8 * h;
    const bool uI = (f == 0) || (f == 1) || (f == 3);
    const float bI = (f == 0) ? 1.f : 0.f;
    const float bT = (f == 1 || f == 2) ? 0.5f : 0.f;
    const float bC = (f == 1 || f == 2) ? 0.5f : ((f >= 3) ? 1.f : 0.f);
    float aI[4], aTC[4];
    int voff[4];
    #pragma unroll
    for (int c = 0; c < 4; ++c) {
        const int gx = gxb + 4 * c;                   // OOB chunks fully OOB (alignment)
        const float m = (yok && gx >= 0 && gx < Wd) ? 1.f : 0.f;
        const int gxc = min(max(gx, 0), Wd - 4);      // clamped, stays 16B-aligned
        voff[c] = gyc * Wd + gxc;
        aI[c]  = uI ? m : 0.f;
        aTC[c] = uI ? 0.f : 0.5f * m;
    }
    const long long nb = (long long)n * ((long long)Dd * HW);
    const float* baseI = inp + nb;
    const float* baseT = tgt + nb;

    // unified store base (both layouts are stride-4 halves): static imm offsets 4*k
    const int stoff = (f < 4) ? ((r * R4) * 4 + 32 * h + f) : (r * RTH + 32 * h);
    half_t* const st0 = (f < 4) ? ((half_t*)xs4h[0] + stoff) : (xsTh[0] + stoff);
    half_t* const st1 = (f < 4) ? ((half_t*)xs4h[1] + stoff) : (xsTh[1] + stoff);

    // ---- phase-2 decode: one output column (yi, xi)
    const int yi = tid >> 4, xi = tid & 15;
    const half4_t* const rd4_0 = &xs4h[0][yi * R4 + xi];
    const half4_t* const rd4_1 = &xs4h[1][yi * R4 + xi];
    const half_t*  const rdT_0 = &xsTh[0][yi * RTH + 4 * xi];
    const half_t*  const rdT_1 = &xsTh[1][yi * RTH + 4 * xi];

    // fp16 z-ring (23 VGPRs); S kept in f32, updated with cvt'd values so the
    // add and the subtract 9 slices later are bit-identical (no drift).
    half2_t r01[9], r23[9]; half_t rT[9];
    #pragma unroll
    for (int q = 0; q < 9; ++q) { r01[q] = (half2_t)0; r23[q] = (half2_t)0; rT[q] = (half_t)0; }
    float4 S4 = make_float4(0.f, 0.f, 0.f, 0.f);
    float ST = 0.f, acc = 0.f;

    float4 Ic[4], Tc[4];
    #pragma unroll
    for (int c = 0; c < 4; ++c) { Ic[c] = make_float4(0.f,0.f,0.f,0.f); Tc[c] = Ic[c]; }

    // prologue: prefetch slice s=0 (zi=z0-4); invalid only for zc==0 (s=0..3 unused then)
    if (z0 - 4 >= 0) {
        const float* pI = baseI + (long long)(z0 - 4) * HW;
        const float* pT = baseT + (long long)(z0 - 4) * HW;
        #pragma unroll
        for (int c = 0; c < 4; ++c) {
            Ic[c] = *(const float4*)(pI + voff[c]);
            Tc[c] = *(const float4*)(pT + voff[c]);
        }
    }

    for (int tb = 0; tb < 36; tb += 18) {          // 28 live slices; 18-unroll -> static slot/parity
        #pragma unroll
        for (int u = 0; u < 18; ++u) {
            const int s = tb + u;                  // block-uniform
            if (s < LIVE) {
                const int zi = z0 - 4 + s;
                const bool zok = (zi >= 0) && (zi < Dd);    // uniform
                const int sl = u % 9;              // static (tb % 9 == 0)
                const int pb = u & 1;              // static plane parity

                // ---- phase-1: consume prefetched regs for slice s
                if (zok) {
                    half_t* const st = pb ? st1 : st0;
                    float p[16];
                    #pragma unroll
                    for (int c = 0; c < 4; ++c) {
                        const float iv[4] = {Ic[c].x, Ic[c].y, Ic[c].z, Ic[c].w};
                        const float tv[4] = {Tc[c].x, Tc[c].y, Tc[c].z, Tc[c].w};
                        #pragma unroll
                        for (int q2 = 0; q2 < 4; ++q2) {
                            const float uu = fmaf(iv[q2], aI[c], fmaf(tv[q2], aTC[c], aTC[c]));
                            const float vv = fmaf(iv[q2], bI,    fmaf(tv[q2], bT,    bC));
                            p[4*c + q2] = uu * vv;
                        }
                    }
                    float ssum = 0.f;
                    #pragma unroll
                    for (int q = 0; q < 9; ++q) ssum += p[q];
                    float o[8]; o[0] = ssum;
                    #pragma unroll
                    for (int k = 1; k < 8; ++k) { ssum += p[k + 8] - p[k - 1]; o[k] = ssum; }
                    #pragma unroll
                    for (int k = 0; k < 8; ++k) st[4 * k] = (half_t)o[k];  // static 8B-stride imms
                }

                // ---- prefetch slice s+1 (consumed after next barrier)
                {
                    const int zi2 = z0 - 3 + s;
                    if ((s + 1) < LIVE && zi2 >= 0 && zi2 < Dd) {          // uniform
                        const float* pI = baseI + (long long)zi2 * HW;
                        const float* pT = baseT + (long long)zi2 * HW;
                        #pragma unroll
                        for (int c = 0; c < 4; ++c) {
                            Ic[c] = *(const float4*)(pI + voff[c]);
                            Tc[c] = *(const float4*)(pT + voff[c]);
                        }
                    }
                }

                __syncthreads();                   // single barrier per slice

                // ---- phase-2: fp16 y-taps (v_pk_add_f16), f32 z-window, cc
                half2_t a01 = (half2_t)0, a23 = (half2_t)0;
                half_t aT = (half_t)0;
                if (zok) {
                    const half4_t* const rd4 = pb ? rd4_1 : rd4_0;
                    const half_t*  const rdT = pb ? rdT_1 : rdT_0;
                    #pragma unroll
                    for (int k = 0; k < 9; ++k) {
                        const half4_t v = rd4[k * R4];
                        const half2_t vlo = {v.x, v.y};
                        const half2_t vhi = {v.z, v.w};
                        a01 += vlo; a23 += vhi;
                        aT += rdT[k * RTH];
                    }
                }
                S4.x += (float)a01.x - (float)r01[sl].x;
                S4.y += (float)a01.y - (float)r01[sl].y;
                S4.z += (float)a23.x - (float)r23[sl].x;
                S4.w += (float)a23.y - (float)r23[sl].y;
                ST   += (float)aT    - (float)rT[sl];
                r01[sl] = a01; r23[sl] = a23; rT[sl] = aT;

                if (s >= 8) {                      // output voxel z = z0 + s - 8
                    const float sii = S4.x, sit = S4.y, stt = S4.z, si = S4.w, stv = ST;
                    const float cross = sit - si * stv * INV_K;
                    const float tvar  = stt - stv * stv * INV_K;
                    const float ivar  = sii - si  * si  * INV_K;
                    acc += cross * cross * __builtin_amdgcn_rcpf(tvar * ivar + 1e-5f);
                }
            }
        }
    }

    // ---- block reduction + fused finalize (one atomic per block)
    #pragma unroll
    for (int off = 32; off > 0; off >>= 1) acc += __shfl_down(acc, off, 64);
    if ((tid & 63) == 0) red[tid >> 6] = acc;
    __syncthreads();
    if (tid == 0) {
        const float tot = red[0] + red[1] + red[2] + red[3];
        atomicAdd(out, -tot * INV_TOT);
    }
}

} // namespace

extern "C" void kernel_launch(void* const* d_in, const int* in_sizes, int n_in,
                              void* d_out, int out_size, void* d_ws, size_t ws_size,
                              hipStream_t stream)
{
    const float* inp = (const float*)d_in[0];
    const float* tgt = (const float*)d_in[1];
    float* out = (float*)d_out;

    hipMemsetAsync(d_out, 0, sizeof(float), stream);   // d_out re-poisoned each call
    dim3 grid(Wd / TX, Hd / TY, 2 * (Dd / CZ));        // (10,12,16) = 1920 blocks
    ncc_main<<<grid, 256, 0, stream>>>(inp, tgt, out);
}

// Round 5
// 210.999 us; speedup vs baseline: 1.6442x; 1.6442x over previous
//
#include <hip/hip_runtime.h>

namespace {

typedef _Float16 half_t;
typedef _Float16 half2_t __attribute__((ext_vector_type(2)));
typedef _Float16 half4_t __attribute__((ext_vector_type(4)));

constexpr int Wd = 160, Hd = 192, Dd = 160;
constexpr int TX = 16, TY = 16, CZ = 40;
constexpr int HW = Hd * Wd;
constexpr int LIVE = CZ + 8;               // 48 slices per block
constexpr float INV_K = 1.0f / 729.0f;
constexpr float INV_TOT = 1.0f / 9830400.0f;   // 2*160*192*160
constexpr int R4 = 17;     // xs4h row stride in half4 units (16 cols + 1 pad)
constexpr int RTH = 68;    // xsTh row stride in half units (x at 4*x)
constexpr int ROWS = 26;   // 24 halo rows + 2 pad rows absorbing lanes 240..255

// Fields f: 0=II 1=IT 2=TT 3=I (xs4h half4) 4=T (xsTh). T scaled (t+1)*0.5;
// zero padding applied AFTER scaling (OOB masks folded into fma coefficients).
// fp16 planes+ring verified numerically in round 4 (passed, absmax ~0).

__global__ __launch_bounds__(256, 4)   // cap 128 VGPRs: demand ~105, must NOT spill
void ncc_main(const float* __restrict__ inp, const float* __restrict__ tgt,
              float* __restrict__ out)
{
    __shared__ half4_t xs4h[2][ROWS * R4];   // 2 x 3536 B
    __shared__ half_t  xsTh[2][ROWS * RTH];  // 2 x 3536 B
    __shared__ float   red[4];

    const int tid = threadIdx.x;
    const int n  = (int)blockIdx.z >> 2;
    const int zc = (int)blockIdx.z & 3;
    const int x0 = blockIdx.x * TX, y0 = blockIdx.y * TY, z0 = zc * CZ;

    // ---- phase-1 decode: (row r 0..25) x (half h) x (field f)
    const int f = tid % 5;
    const int j = tid / 5;
    const int r = j >> 1, h = j & 1;
    const int gy = y0 - 4 + r;
    const bool yok = (tid < 240) && (gy >= 0) && (gy < Hd);
    const int gyc = min(max(gy, 0), Hd - 1);
    const int gxb = x0 - 4 + 8 * h;
    const bool uI = (f == 0) || (f == 1) || (f == 3);
    const float bI = (f == 0) ? 1.f : 0.f;
    const float bT = (f == 1 || f == 2) ? 0.5f : 0.f;
    const float bC = (f == 1 || f == 2) ? 0.5f : ((f >= 3) ? 1.f : 0.f);
    float aI[4], aTC[4];
    int voff[4];
    #pragma unroll
    for (int c = 0; c < 4; ++c) {
        const int gx = gxb + 4 * c;                   // OOB chunks fully OOB (alignment)
        const float m = (yok && gx >= 0 && gx < Wd) ? 1.f : 0.f;
        const int gxc = min(max(gx, 0), Wd - 4);      // clamped, stays 16B-aligned
        voff[c] = gyc * Wd + gxc;
        aI[c]  = uI ? m : 0.f;
        aTC[c] = uI ? 0.f : 0.5f * m;
    }
    const long long nb = (long long)n * ((long long)Dd * HW);
    const float* baseI = inp + nb;   // uniform -> SGPR pair; loads saddr-form
    const float* baseT = tgt + nb;

    // unified store base (both layouts are stride-4 halves): static imm offsets 4*k
    const int stoff = (f < 4) ? ((r * R4) * 4 + 32 * h + f) : (r * RTH + 32 * h);
    half_t* const st0 = (f < 4) ? ((half_t*)xs4h[0] + stoff) : (xsTh[0] + stoff);
    half_t* const st1 = (f < 4) ? ((half_t*)xs4h[1] + stoff) : (xsTh[1] + stoff);

    // ---- phase-2 decode: one output column (yi, xi)
    const int yi = tid >> 4, xi = tid & 15;
    const half4_t* const rd4_0 = &xs4h[0][yi * R4 + xi];
    const half4_t* const rd4_1 = &xs4h[1][yi * R4 + xi];
    const half_t*  const rdT_0 = &xsTh[0][yi * RTH + 4 * xi];
    const half_t*  const rdT_1 = &xsTh[1][yi * RTH + 4 * xi];

    // ring: fp16 for the 4 packed fields (18 VGPRs), f32 for T (9 VGPRs).
    // S in f32: add and subtract of the same cvt'd value 9 slices apart -> no drift.
    half2_t r01[9], r23[9]; float rT[9];
    #pragma unroll
    for (int q = 0; q < 9; ++q) { r01[q] = (half2_t)0; r23[q] = (half2_t)0; rT[q] = 0.f; }
    float4 S4 = make_float4(0.f, 0.f, 0.f, 0.f);
    float ST = 0.f, acc = 0.f;

    float4 Ic[4], Tc[4];
    #pragma unroll
    for (int c = 0; c < 4; ++c) { Ic[c] = make_float4(0.f,0.f,0.f,0.f); Tc[c] = Ic[c]; }

    // prologue: prefetch slice s=0 (zi=z0-4); invalid only for zc==0 (s=0..3 unused then)
    if (z0 - 4 >= 0) {
        const float* pI = baseI + (long long)(z0 - 4) * HW;
        const float* pT = baseT + (long long)(z0 - 4) * HW;
        #pragma unroll
        for (int c = 0; c < 4; ++c) {
            Ic[c] = *(const float4*)(pI + voff[c]);
            Tc[c] = *(const float4*)(pT + voff[c]);
        }
    }

    for (int tb = 0; tb < 54; tb += 18) {          // 48 live slices; 18-unroll -> static slot/parity
        #pragma unroll
        for (int u = 0; u < 18; ++u) {
            const int s = tb + u;                  // block-uniform
            if (s < LIVE) {
                const int zi = z0 - 4 + s;
                const bool zok = (zi >= 0) && (zi < Dd);    // uniform
                const int sl = u % 9;              // static (tb % 9 == 0)
                const int pb = u & 1;              // static plane parity

                // ---- phase-1a: products from prefetched regs (frees Ic/Tc early)
                float p[16];
                if (zok) {
                    #pragma unroll
                    for (int c = 0; c < 4; ++c) {
                        const float iv[4] = {Ic[c].x, Ic[c].y, Ic[c].z, Ic[c].w};
                        const float tv[4] = {Tc[c].x, Tc[c].y, Tc[c].z, Tc[c].w};
                        #pragma unroll
                        for (int q2 = 0; q2 < 4; ++q2) {
                            const float uu = fmaf(iv[q2], aI[c], fmaf(tv[q2], aTC[c], aTC[c]));
                            const float vv = fmaf(iv[q2], bI,    fmaf(tv[q2], bT,    bC));
                            p[4*c + q2] = uu * vv;
                        }
                    }
                }

                // ---- prefetch slice s+1 (in flight over stores + barrier + phase-2)
                {
                    const int zi2 = z0 - 3 + s;
                    if ((s + 1) < LIVE && zi2 >= 0 && zi2 < Dd) {          // uniform
                        const float* pI = baseI + (long long)zi2 * HW;
                        const float* pT = baseT + (long long)zi2 * HW;
                        #pragma unroll
                        for (int c = 0; c < 4; ++c) {
                            Ic[c] = *(const float4*)(pI + voff[c]);
                            Tc[c] = *(const float4*)(pT + voff[c]);
                        }
                    }
                }

                // ---- phase-1b: sliding x-window, fp16 stores to plane[pb]
                if (zok) {
                    half_t* const st = pb ? st1 : st0;
                    float ssum = 0.f;
                    #pragma unroll
                    for (int q = 0; q < 9; ++q) ssum += p[q];
                    st[0] = (half_t)ssum;
                    #pragma unroll
                    for (int k = 1; k < 8; ++k) {
                        ssum += p[k + 8] - p[k - 1];
                        st[4 * k] = (half_t)ssum;   // static 8B-stride imm offsets
                    }
                }

                __syncthreads();                   // single barrier per slice

                // ---- phase-2: fp16 y-taps (v_pk_add_f16), f32 z-window, cc
                half2_t a01 = (half2_t)0, a23 = (half2_t)0;
                half_t aT = (half_t)0;
                if (zok) {
                    const half4_t* const rd4 = pb ? rd4_1 : rd4_0;
                    const half_t*  const rdT = pb ? rdT_1 : rdT_0;
                    #pragma unroll
                    for (int k = 0; k < 9; ++k) {
                        const half4_t v = rd4[k * R4];
                        const half2_t vlo = {v.x, v.y};
                        const half2_t vhi = {v.z, v.w};
                        a01 += vlo; a23 += vhi;
                        aT += rdT[k * RTH];
                    }
                }
                const float aTf = (float)aT;
                S4.x += (float)a01.x - (float)r01[sl].x;
                S4.y += (float)a01.y - (float)r01[sl].y;
                S4.z += (float)a23.x - (float)r23[sl].x;
                S4.w += (float)a23.y - (float)r23[sl].y;
                ST   += aTf - rT[sl];
                r01[sl] = a01; r23[sl] = a23; rT[sl] = aTf;

                if (s >= 8) {                      // output voxel z = z0 + s - 8
                    const float sii = S4.x, sit = S4.y, stt = S4.z, si = S4.w, stv = ST;
                    const float cross = sit - si * stv * INV_K;
                    const float tvar  = stt - stv * stv * INV_K;
                    const float ivar  = sii - si  * si  * INV_K;
                    acc += cross * cross * __builtin_amdgcn_rcpf(tvar * ivar + 1e-5f);
                }
            }
        }
    }

    // ---- block reduction + fused finalize (one atomic per block)
    #pragma unroll
    for (int off = 32; off > 0; off >>= 1) acc += __shfl_down(acc, off, 64);
    if ((tid & 63) == 0) red[tid >> 6] = acc;
    __syncthreads();
    if (tid == 0) {
        const float tot = red[0] + red[1] + red[2] + red[3];
        atomicAdd(out, -tot * INV_TOT);
    }
}

} // namespace

extern "C" void kernel_launch(void* const* d_in, const int* in_sizes, int n_in,
                              void* d_out, int out_size, void* d_ws, size_t ws_size,
                              hipStream_t stream)
{
    const float* inp = (const float*)d_in[0];
    const float* tgt = (const float*)d_in[1];
    float* out = (float*)d_out;

    hipMemsetAsync(d_out, 0, sizeof(float), stream);   // d_out re-poisoned each call
    dim3 grid(Wd / TX, Hd / TY, 2 * (Dd / CZ));        // (10,12,8) = 960 blocks
    ncc_main<<<grid, 256, 0, stream>>>(inp, tgt, out);
}

// Round 6
// 187.102 us; speedup vs baseline: 1.8543x; 1.1277x over previous
//
#include <hip/hip_runtime.h>

namespace {

typedef _Float16 half_t;
typedef _Float16 half2_t __attribute__((ext_vector_type(2)));
typedef _Float16 half4_t __attribute__((ext_vector_type(4)));

constexpr int Wd = 160, Hd = 192, Dd = 160;
constexpr int TX = 16, TY = 16, CZ = 40;
constexpr int HW = Hd * Wd;
constexpr int LIVE = CZ + 8;               // 48 slices per block
constexpr float INV_K = 1.0f / 729.0f;
constexpr float INV_TOT = 1.0f / 9830400.0f;   // 2*160*192*160
constexpr int R4 = 17;     // xs4h row stride in half4 units (16 cols + 1 pad)
constexpr int RTH = 68;    // xsTh row stride in half units (x at 4*x)
constexpr int ROWS = 26;   // 24 halo rows + 2 pad rows absorbing lanes 240..255

// NOTE (round 6): all hot-loop state is in NAMED SCALARS, no local arrays.
// Rounds 3-5 showed 145-411 MB of scratch traffic (WRITE_SIZE) with
// VGPR_Count stuck at 64: the prefetch/ring arrays were living in scratch
// allocas instead of being SROA'd. Named variables cannot fail promotion.
// The z-ring is a shift register: inside the 18x-unrolled body the shifts
// are SSA renames (free); 18 = 2*9 so the tb back-edge mapping is identity.

__global__ __launch_bounds__(256, 4)   // cap 128 VGPRs; demand ~105
void ncc_main(const float* __restrict__ inp, const float* __restrict__ tgt,
              float* __restrict__ out)
{
    __shared__ half4_t xs4h[2][ROWS * R4];   // 2 x 3536 B
    __shared__ half_t  xsTh[2][ROWS * RTH];  // 2 x 3536 B
    __shared__ float   red[4];

    const int tid = threadIdx.x;
    const int n  = (int)blockIdx.z >> 2;
    const int zc = (int)blockIdx.z & 3;
    const int x0 = blockIdx.x * TX, y0 = blockIdx.y * TY, z0 = zc * CZ;

    // ---- phase-1 decode: (row r 0..25) x (half h) x (field f)
    const int f = tid % 5;
    const int j = tid / 5;
    const int r = j >> 1, h = j & 1;
    const int gy = y0 - 4 + r;
    const bool yok = (tid < 240) && (gy >= 0) && (gy < Hd);
    const int gyc = min(max(gy, 0), Hd - 1);
    const int gxb = x0 - 4 + 8 * h;
    const bool uI = (f == 0) || (f == 1) || (f == 3);
    const float bI = (f == 0) ? 1.f : 0.f;
    const float bT = (f == 1 || f == 2) ? 0.5f : 0.f;
    const float bC = (f == 1 || f == 2) ? 0.5f : ((f >= 3) ? 1.f : 0.f);

#define DECODE(c) \
    int voff##c; float aI##c, aTC##c; \
    { const int gx = gxb + 4 * c; \
      const float m = (yok && gx >= 0 && gx < Wd) ? 1.f : 0.f; \
      const int gxc = min(max(gx, 0), Wd - 4); \
      voff##c = gyc * Wd + gxc; \
      aI##c = uI ? m : 0.f; aTC##c = uI ? 0.f : 0.5f * m; }
    DECODE(0) DECODE(1) DECODE(2) DECODE(3)
#undef DECODE

    const int nb = n * (Dd * HW);            // < 2^24, int math is exact
    const float* baseI = inp + nb;           // uniform -> SGPR pair
    const float* baseT = tgt + nb;

    // unified store base (both layouts are stride-4 halves): static imm offsets
    const int stoff = (f < 4) ? ((r * R4) * 4 + 32 * h + f) : (r * RTH + 32 * h);
    half_t* const st0 = (f < 4) ? ((half_t*)xs4h[0] + stoff) : (xsTh[0] + stoff);
    half_t* const st1 = (f < 4) ? ((half_t*)xs4h[1] + stoff) : (xsTh[1] + stoff);

    // ---- phase-2 decode: one output column (yi, xi)
    const int yi = tid >> 4, xi = tid & 15;
    const half4_t* const rd4_0 = &xs4h[0][yi * R4 + xi];
    const half4_t* const rd4_1 = &xs4h[1][yi * R4 + xi];
    const half_t*  const rdT_0 = &xsTh[0][yi * RTH + 4 * xi];
    const half_t*  const rdT_1 = &xsTh[1][yi * RTH + 4 * xi];

    // z-ring as NAMED shift-register slots (27 VGPRs). S in f32: add and
    // subtract of the same cvt'd value 9 slices apart -> no drift.
    const half2_t hz = {(half_t)0.f, (half_t)0.f};
    half2_t R01_0=hz,R01_1=hz,R01_2=hz,R01_3=hz,R01_4=hz,R01_5=hz,R01_6=hz,R01_7=hz,R01_8=hz;
    half2_t R23_0=hz,R23_1=hz,R23_2=hz,R23_3=hz,R23_4=hz,R23_5=hz,R23_6=hz,R23_7=hz,R23_8=hz;
    float   RT_0=0.f,RT_1=0.f,RT_2=0.f,RT_3=0.f,RT_4=0.f,RT_5=0.f,RT_6=0.f,RT_7=0.f,RT_8=0.f;
    float4 S4 = make_float4(0.f, 0.f, 0.f, 0.f);
    float ST = 0.f, acc = 0.f;

    float4 Ic0, Ic1, Ic2, Ic3, Tc0, Tc1, Tc2, Tc3;
    Ic0 = Ic1 = Ic2 = Ic3 = make_float4(0.f, 0.f, 0.f, 0.f);
    Tc0 = Tc1 = Tc2 = Tc3 = Ic0;

#define PRELOAD(zz) { \
    const float* pI = baseI + (zz) * HW; \
    const float* pT = baseT + (zz) * HW; \
    Ic0 = *(const float4*)(pI + voff0); Tc0 = *(const float4*)(pT + voff0); \
    Ic1 = *(const float4*)(pI + voff1); Tc1 = *(const float4*)(pT + voff1); \
    Ic2 = *(const float4*)(pI + voff2); Tc2 = *(const float4*)(pT + voff2); \
    Ic3 = *(const float4*)(pI + voff3); Tc3 = *(const float4*)(pT + voff3); }

    // prologue: prefetch slice s=0 (zi=z0-4); invalid only for zc==0
    if (z0 - 4 >= 0) PRELOAD(z0 - 4)

#define PRODC(c, P0, P1, P2, P3) { \
    P0 = fmaf(Ic##c.x, aI##c, fmaf(Tc##c.x, aTC##c, aTC##c)) * fmaf(Ic##c.x, bI, fmaf(Tc##c.x, bT, bC)); \
    P1 = fmaf(Ic##c.y, aI##c, fmaf(Tc##c.y, aTC##c, aTC##c)) * fmaf(Ic##c.y, bI, fmaf(Tc##c.y, bT, bC)); \
    P2 = fmaf(Ic##c.z, aI##c, fmaf(Tc##c.z, aTC##c, aTC##c)) * fmaf(Ic##c.z, bI, fmaf(Tc##c.z, bT, bC)); \
    P3 = fmaf(Ic##c.w, aI##c, fmaf(Tc##c.w, aTC##c, aTC##c)) * fmaf(Ic##c.w, bI, fmaf(Tc##c.w, bT, bC)); }

#define SHIFT9(P, NV) \
    P##_0 = P##_1; P##_1 = P##_2; P##_2 = P##_3; P##_3 = P##_4; P##_4 = P##_5; \
    P##_5 = P##_6; P##_6 = P##_7; P##_7 = P##_8; P##_8 = (NV);

    for (int tb = 0; tb < 54; tb += 18) {          // 48 live; 18-unroll -> static parity
        #pragma unroll
        for (int u = 0; u < 18; ++u) {
            const int s = tb + u;                  // block-uniform
            if (s < LIVE) {
                const int zi = z0 - 4 + s;
                const bool zok = (zi >= 0) && (zi < Dd);    // uniform
                const int pb = u & 1;              // static plane parity

                // ---- phase-1a: products from prefetched regs (named p0..p15)
                float p0, p1, p2, p3, p4, p5, p6, p7, p8, p9, p10, p11, p12, p13, p14, p15;
                if (zok) {
                    PRODC(0, p0,  p1,  p2,  p3)
                    PRODC(1, p4,  p5,  p6,  p7)
                    PRODC(2, p8,  p9,  p10, p11)
                    PRODC(3, p12, p13, p14, p15)
                }

                // ---- prefetch slice s+1 (in flight over stores+barrier+phase-2)
                {
                    const int zi2 = z0 - 3 + s;
                    if ((s + 1) < LIVE && zi2 >= 0 && zi2 < Dd) PRELOAD(zi2)
                }

                // ---- phase-1b: sliding x-window, fp16 stores to plane[pb]
                if (zok) {
                    half_t* const st = pb ? st1 : st0;
                    float ss = p0 + p1 + p2 + p3 + p4 + p5 + p6 + p7 + p8;
                    st[0]  = (half_t)ss;
                    ss += p9  - p0; st[4]  = (half_t)ss;
                    ss += p10 - p1; st[8]  = (half_t)ss;
                    ss += p11 - p2; st[12] = (half_t)ss;
                    ss += p12 - p3; st[16] = (half_t)ss;
                    ss += p13 - p4; st[20] = (half_t)ss;
                    ss += p14 - p5; st[24] = (half_t)ss;
                    ss += p15 - p6; st[28] = (half_t)ss;
                }

                __syncthreads();                   // single barrier per slice

                // ---- phase-2: fp16 y-taps (v_pk_add_f16), f32 z-window, cc
                half2_t a01 = hz, a23 = hz;
                float aTf = 0.f;
                if (zok) {
                    const half4_t* const rd4 = pb ? rd4_1 : rd4_0;
                    const half_t*  const rdT = pb ? rdT_1 : rdT_0;
                    half_t aT = (half_t)0.f;
                    #pragma unroll
                    for (int k = 0; k < 9; ++k) {
                        const half4_t v = rd4[k * R4];
                        const half2_t vlo = {v.x, v.y};
                        const half2_t vhi = {v.z, v.w};
                        a01 += vlo; a23 += vhi;
                        aT += rdT[k * RTH];
                    }
                    aTf = (float)aT;
                }

                // S update + ring shift (unconditional: pad slices insert 0)
                S4.x += (float)a01.x - (float)R01_0.x;
                S4.y += (float)a01.y - (float)R01_0.y;
                S4.z += (float)a23.x - (float)R23_0.x;
                S4.w += (float)a23.y - (float)R23_0.y;
                ST   += aTf - RT_0;
                SHIFT9(R01, a01)
                SHIFT9(R23, a23)
                SHIFT9(RT, aTf)

                if (s >= 8) {                      // output voxel z = z0 + s - 8
                    const float sii = S4.x, sit = S4.y, stt = S4.z, si = S4.w, stv = ST;
                    const float cross = sit - si * stv * INV_K;
                    const float tvar  = stt - stv * stv * INV_K;
                    const float ivar  = sii - si  * si  * INV_K;
                    acc += cross * cross * __builtin_amdgcn_rcpf(tvar * ivar + 1e-5f);
                }
            }
        }
    }
#undef PRELOAD
#undef PRODC
#undef SHIFT9

    // ---- block reduction + fused finalize (one atomic per block)
    #pragma unroll
    for (int off = 32; off > 0; off >>= 1) acc += __shfl_down(acc, off, 64);
    if ((tid & 63) == 0) red[tid >> 6] = acc;
    __syncthreads();
    if (tid == 0) {
        const float tot = red[0] + red[1] + red[2] + red[3];
        atomicAdd(out, -tot * INV_TOT);
    }
}

} // namespace

extern "C" void kernel_launch(void* const* d_in, const int* in_sizes, int n_in,
                              void* d_out, int out_size, void* d_ws, size_t ws_size,
                              hipStream_t stream)
{
    const float* inp = (const float*)d_in[0];
    const float* tgt = (const float*)d_in[1];
    float* out = (float*)d_out;

    hipMemsetAsync(d_out, 0, sizeof(float), stream);   // d_out re-poisoned each call
    dim3 grid(Wd / TX, Hd / TY, 2 * (Dd / CZ));        // (10,12,8) = 960 blocks
    ncc_main<<<grid, 256, 0, stream>>>(inp, tgt, out);
}